// Round 2
// baseline (181.039 us; speedup 1.0000x reference)
//
#include <hip/hip_runtime.h>
#include <hip/hip_bf16.h>

// B=4, G=1024, D=512, H=8, dh=64. NUM_BUCKETS=32, MAX_DIST=128, base=2.
typedef __attribute__((ext_vector_type(8))) short bf16x8;
typedef __attribute__((ext_vector_type(4))) float f32x4;

__device__ __forceinline__ unsigned short f2bf(float x) {
  union { __hip_bfloat16 h; unsigned short u; } cv;
  cv.h = __float2bfloat16(x);
  return cv.u;
}

__device__ __forceinline__ void gload16(const void* g, void* l) {
  __builtin_amdgcn_global_load_lds(
      (const __attribute__((address_space(1))) unsigned int*)g,
      (__attribute__((address_space(3))) unsigned int*)l, 16, 0, 0);
}

// swizzled byte offset for 128B-row LDS tiles
__device__ __forceinline__ int swz128(int row, int colb) {
  return row * 128 + (colb ^ ((row & 7) << 4));
}

// ---------------- fp32 -> bf16 conversion (all tensors, one launch) -------------
__global__ __launch_bounds__(256)
void k_cvt_all(const float* __restrict__ q, const float* __restrict__ k,
               const float* __restrict__ v, const float* __restrict__ Wq,
               const float* __restrict__ Wk, const float* __restrict__ Wv,
               const float* __restrict__ Wo,
               unsigned short* __restrict__ XQ, unsigned short* __restrict__ XK,
               unsigned short* __restrict__ XV, unsigned short* __restrict__ WQB,
               unsigned short* __restrict__ WKB, unsigned short* __restrict__ WVB,
               unsigned short* __restrict__ WOB)
{
  long i = ((long)blockIdx.x * 256 + threadIdx.x) * 8;
  const float* s; unsigned short* d; long off;
  if (i < 2097152)      { s = q; d = XQ; off = i; }
  else if (i < 4194304) { s = k; d = XK; off = i - 2097152; }
  else if (i < 6291456) { s = v; d = XV; off = i - 4194304; }
  else {
    long j = i - 6291456;
    int wsel = (int)(j >> 18);
    off = j & 262143;
    s = wsel == 0 ? Wq : wsel == 1 ? Wk : wsel == 2 ? Wv : Wo;
    d = wsel == 0 ? WQB : wsel == 1 ? WKB : wsel == 2 ? WVB : WOB;
  }
  float4 a = *(const float4*)(s + off);
  float4 bb = *(const float4*)(s + off + 4);
  bf16x8 o;
  o[0] = (short)f2bf(a.x);  o[1] = (short)f2bf(a.y);
  o[2] = (short)f2bf(a.z);  o[3] = (short)f2bf(a.w);
  o[4] = (short)f2bf(bb.x); o[5] = (short)f2bf(bb.y);
  o[6] = (short)f2bf(bb.z); o[7] = (short)f2bf(bb.w);
  *(bf16x8*)(d + off) = o;
}

// ---------------- per-batch valid-key compaction (prefix scan) ------------------
__global__ __launch_bounds__(1024)
void k_scan(const int* __restrict__ mask, int* __restrict__ idx, int* __restrict__ cnt) {
  __shared__ int ps[1024];
  int b = blockIdx.x, t = threadIdx.x;
  int m = mask[(b << 10) + t];
  ps[t] = m;
  __syncthreads();
  #pragma unroll
  for (int off = 1; off < 1024; off <<= 1) {
    int v = (t >= off) ? ps[t - off] : 0;
    __syncthreads();
    ps[t] += v;
    __syncthreads();
  }
  if (m) idx[(b << 10) + ps[t] - 1] = t;
  if (t == 1023) cnt[b] = ps[t];
}

// ---------------- compacted relative-position buckets ---------------------------
__device__ __forceinline__ int rbucket(float dd) {
  float ad = fabsf(dd);
  float n = fminf(fmaxf(ad, 1e-6f), 128.0f);
  int li = (int)floorf(logf(n) * 1.4426950408889634f);
  li = li < 0 ? 0 : (li > 31 ? 31 : li);
  int s = (dd > 0.f) ? 1 : ((dd < 0.f) ? -1 : 0);
  return li * s + 31;
}

__global__ __launch_bounds__(256)
void k_buckets_c(const float* __restrict__ coords, const int* __restrict__ idx,
                 const int* __restrict__ cnt, unsigned short* __restrict__ buk) {
  int b = blockIdx.y;
  int f = blockIdx.x * 256 + threadIdx.x;   // q*1024 + ck
  int qi = f >> 10, ck = f & 1023;
  if (ck >= cnt[b]) return;
  int ki = idx[(b << 10) + ck];
  const float* cb = coords + (b << 11);
  float dx = cb[qi * 2] - cb[ki * 2];
  float dy = cb[qi * 2 + 1] - cb[ki * 2 + 1];
  int bx = rbucket(dx);
  int by = rbucket(dy);
  buk[((long)(b << 10) + qi) * 1024 + ck] = (unsigned short)(bx | (by << 8));
}

// ---------------- gather compacted K rows + transposed V ------------------------
__global__ __launch_bounds__(256)
void k_gatherKV(const unsigned short* __restrict__ KP,
                const unsigned short* __restrict__ VTMP,
                const int* __restrict__ idx, const int* __restrict__ cnt,
                unsigned short* __restrict__ KC, unsigned short* __restrict__ VCT)
{
  __shared__ unsigned short tile[64][68];
  __shared__ int lidx[64];
  int bh = blockIdx.y, b = bh >> 3;
  int cn = cnt[b];
  int ck0 = blockIdx.x << 6;
  if (ck0 >= cn) return;
  int t = threadIdx.x;
  if (t < 64) lidx[t] = idx[(b << 10) + min(ck0 + t, cn - 1)];
  __syncthreads();
  int r = t >> 2, qd = t & 3;
  long srcrow = ((long)(bh << 10) + lidx[r]) * 64;
  long dstrow = ((long)(bh << 10) + ck0 + r) * 64;
  uint4 kv0 = *(const uint4*)(KP + srcrow + qd * 16);
  uint4 kv1 = *(const uint4*)(KP + srcrow + qd * 16 + 8);
  *(uint4*)(KC + dstrow + qd * 16) = kv0;
  *(uint4*)(KC + dstrow + qd * 16 + 8) = kv1;
  const uint2* vsrc = (const uint2*)(VTMP + srcrow + qd * 16);
  #pragma unroll
  for (int s = 0; s < 4; ++s)
    *(uint2*)(&tile[r][qd * 16 + s * 4]) = vsrc[s];
  __syncthreads();
  #pragma unroll
  for (int it = 0; it < 16; ++it) {
    int d = it * 4 + (t >> 6);
    int ck = t & 63;
    VCT[((long)(bh << 6) + d) * 1024 + ck0 + ck] = tile[ck][d];
  }
}

// ---------------- GEMM core: C = A(M,512) @ Bw(N,512)^T, 128x64 tile, 4 waves ---
__device__ __forceinline__ void gemm_core64(
    const unsigned short* __restrict__ A, const unsigned short* __restrict__ Bw,
    int m0, int n0, unsigned short* ldsA, unsigned short* ldsB, f32x4 acc[4][2])
{
  const int t = threadIdx.x;
  const int lane = t & 63;
  const int w = t >> 6;
  const int wm = (w >> 1) << 6;
  const int wn = (w & 1) << 5;
  const int l15 = lane & 15;
  const int l4 = lane >> 4;
  const f32x4 fz = {0.f, 0.f, 0.f, 0.f};

  #pragma unroll
  for (int r = 0; r < 4; ++r)
    #pragma unroll
    for (int c = 0; c < 2; ++c) acc[r][c] = fz;

  for (int k0 = 0; k0 < 512; k0 += 32) {
    #pragma unroll
    for (int rr = 0; rr < 2; ++rr) {
      int c = rr * 256 + t;
      int row = c >> 2, cc = c & 3;
      gload16(A + (m0 + row) * 512 + k0 + cc * 8, (char*)ldsA + c * 16);
    }
    {
      int c = t;
      int row = c >> 2, cc = c & 3;
      gload16(Bw + (n0 + row) * 512 + k0 + cc * 8, (char*)ldsB + c * 16);
    }
    __syncthreads();
    bf16x8 af[4], bfr[2];
    #pragma unroll
    for (int r = 0; r < 4; ++r)
      af[r] = *(const bf16x8*)((const char*)ldsA + (wm + r * 16 + l15) * 64 + l4 * 16);
    #pragma unroll
    for (int c = 0; c < 2; ++c)
      bfr[c] = *(const bf16x8*)((const char*)ldsB + (wn + c * 16 + l15) * 64 + l4 * 16);
    #pragma unroll
    for (int r = 0; r < 4; ++r)
      #pragma unroll
      for (int c = 0; c < 2; ++c)
        acc[r][c] = __builtin_amdgcn_mfma_f32_16x16x32_bf16(af[r], bfr[c], acc[r][c], 0, 0, 0);
    __syncthreads();
  }
}

// ---------------- Q/K/V projections -> (B,H,G,64) bf16 --------------------------
__global__ __launch_bounds__(256)
void k_gemm_proj(const unsigned short* __restrict__ XQ, const unsigned short* __restrict__ XK,
                 const unsigned short* __restrict__ XV, const unsigned short* __restrict__ WQ,
                 const unsigned short* __restrict__ WK, const unsigned short* __restrict__ WV,
                 const float* __restrict__ bq, const float* __restrict__ bk,
                 const float* __restrict__ bv,
                 unsigned short* __restrict__ QP, unsigned short* __restrict__ KP,
                 unsigned short* __restrict__ VT)
{
  __shared__ unsigned short ldsA[128 * 32];
  __shared__ unsigned short ldsB[64 * 32];
  int z = blockIdx.z;
  const unsigned short* A = z == 0 ? XQ : z == 1 ? XK : XV;
  const unsigned short* W = z == 0 ? WQ : z == 1 ? WK : WV;
  const float* bias = z == 0 ? bq : z == 1 ? bk : bv;
  unsigned short* dst = z == 0 ? QP : z == 1 ? KP : VT;
  int m0 = blockIdx.x * 128, n0 = blockIdx.y * 64;
  f32x4 acc[4][2];
  gemm_core64(A, W, m0, n0, ldsA, ldsB, acc);

  const int t = threadIdx.x, lane = t & 63, w = t >> 6;
  const int wm = (w >> 1) << 6, wn = (w & 1) << 5;
  const int l15 = lane & 15, l4 = lane >> 4;
  #pragma unroll
  for (int r = 0; r < 4; ++r)
    #pragma unroll
    for (int c = 0; c < 2; ++c)
      #pragma unroll
      for (int i = 0; i < 4; ++i) {
        int m = m0 + wm + r * 16 + (l4 << 2) + i;   // token
        int n = n0 + wn + c * 16 + l15;             // channel
        float y = acc[r][c][i] + bias[n];
        int b = m >> 10, g = m & 1023, hh = n >> 6, dd = n & 63;
        dst[((((b << 3) + hh) << 10) + g) * 64 + dd] = f2bf(y);
      }
}

// ---------------- flash attention (compacted keys, no block barriers) -----------
// 1D grid 512 blocks x 4 waves; each wave owns 16 q rows, loops compacted K/V.
__global__ __launch_bounds__(256)
void k_attn(const unsigned short* __restrict__ QP, const unsigned short* __restrict__ KC,
            const unsigned short* __restrict__ VCT, const unsigned short* __restrict__ BUKC,
            const int* __restrict__ cnt, const float* __restrict__ rpe_x,
            const float* __restrict__ rpe_y, unsigned short* __restrict__ AO)
{
  __shared__ float rx[64], ry[64];
  __shared__ unsigned short Ps[4][16 * 64];   // per-wave P-transpose, swizzled 128B rows

  const int t = threadIdx.x;
  const int lane = t & 63;
  const int w = t >> 6;
  const int l15 = lane & 15;
  const int l4 = lane >> 4;
  const f32x4 fz = {0.f, 0.f, 0.f, 0.f};

  // XCD swizzle: group blocks so each XCD handles one batch-half (K/V+BUKC locality)
  int g = blockIdx.x;
  int xcd = g & 7, slot = g >> 3;
  int b = xcd >> 1;
  int qb = ((xcd & 1) << 3) | (slot & 7);
  int h = slot >> 3;
  int bh = (b << 3) | h;
  int qw = (qb << 6) | (w << 4);      // this wave's q-row base

  if (t < 63) { rx[t] = rpe_x[t * 8 + h]; ry[t] = rpe_y[t * 8 + h]; }
  else if (t == 63) { rx[63] = 0.f; ry[63] = 0.f; }
  __syncthreads();

  const unsigned short* Qg = QP + ((long)(bh << 10) + qw) * 64;
  bf16x8 qf[2];
  #pragma unroll
  for (int ks = 0; ks < 2; ++ks)
    qf[ks] = *(const bf16x8*)(Qg + (long)l15 * 64 + ks * 32 + l4 * 8);

  const int cn = cnt[b];
  const int nkt = (cn + 63) >> 6;
  const unsigned short* Kg = KC + ((long)(bh << 10)) * 64;
  const unsigned short* Vg = VCT + ((long)(bh << 6)) * 1024;
  const unsigned short* bukb = BUKC + (((long)(b << 10) + qw) << 10);

  float mrun[4], lrun[4];
  f32x4 oacc[4];
  #pragma unroll
  for (int i = 0; i < 4; ++i) { mrun[i] = -1e30f; lrun[i] = 0.f; }
  #pragma unroll
  for (int dj = 0; dj < 4; ++dj) oacc[dj] = fz;

  unsigned short* Pw = &Ps[w][0];

  for (int kt = 0; kt < nkt; ++kt) {
    const int k0 = kt << 6;
    // bucket loads (independent of MFMA, issued early)
    unsigned short bko[4][4];
    #pragma unroll
    for (int i = 0; i < 4; ++i)
      #pragma unroll
      for (int nj = 0; nj < 4; ++nj)
        bko[i][nj] = bukb[(((long)((l4 << 2) + i)) << 10) + k0 + nj * 16 + l15];

    // S = Q K^T from global K fragments (L1/L2-resident)
    f32x4 sacc[4];
    #pragma unroll
    for (int nj = 0; nj < 4; ++nj) sacc[nj] = fz;
    #pragma unroll
    for (int nj = 0; nj < 4; ++nj)
      #pragma unroll
      for (int ks = 0; ks < 2; ++ks) {
        bf16x8 kf = *(const bf16x8*)(Kg + (long)(k0 + nj * 16 + l15) * 64 + ks * 32 + l4 * 8);
        sacc[nj] = __builtin_amdgcn_mfma_f32_16x16x32_bf16(qf[ks], kf, sacc[nj], 0, 0, 0);
      }

    // online softmax over 16-lane row groups
    float fsc[4];
    float pv_[4][4];
    #pragma unroll
    for (int i = 0; i < 4; ++i) {
      float sv[4];
      float vm = -1e30f;
      #pragma unroll
      for (int nj = 0; nj < 4; ++nj) {
        unsigned bkv = bko[i][nj];
        float bias = rx[bkv & 63] + ry[(bkv >> 8) & 63];
        float s = fmaf(sacc[nj][i], 0.125f, bias);
        s = ((k0 + nj * 16 + l15) < cn) ? s : -1e30f;
        sv[nj] = s;
        vm = fmaxf(vm, s);
      }
      vm = fmaxf(vm, __shfl_xor(vm, 1));
      vm = fmaxf(vm, __shfl_xor(vm, 2));
      vm = fmaxf(vm, __shfl_xor(vm, 4));
      vm = fmaxf(vm, __shfl_xor(vm, 8));
      float mo = mrun[i];
      float mn = fmaxf(mo, vm);
      float f = __expf(mo - mn);
      float ps = 0.f;
      #pragma unroll
      for (int nj = 0; nj < 4; ++nj) {
        float p = __expf(sv[nj] - mn);
        pv_[i][nj] = p;
        ps += p;
      }
      ps += __shfl_xor(ps, 1);
      ps += __shfl_xor(ps, 2);
      ps += __shfl_xor(ps, 4);
      ps += __shfl_xor(ps, 8);
      lrun[i] = lrun[i] * f + ps;
      mrun[i] = mn;
      fsc[i] = f;
    }
    #pragma unroll
    for (int dj = 0; dj < 4; ++dj)
      #pragma unroll
      for (int i = 0; i < 4; ++i) oacc[dj][i] *= fsc[i];

    // P -> wave-private LDS (transpose to MFMA A layout), swizzled
    #pragma unroll
    for (int i = 0; i < 4; ++i) {
      int prow = (l4 << 2) + i;
      #pragma unroll
      for (int nj = 0; nj < 4; ++nj) {
        int pcolb = (nj * 16 + l15) * 2;
        *(unsigned short*)((char*)Pw + swz128(prow, pcolb)) = f2bf(pv_[i][nj]);
      }
    }
    bf16x8 pf[2];
    #pragma unroll
    for (int ks = 0; ks < 2; ++ks)
      pf[ks] = *(const bf16x8*)((const char*)Pw + swz128(l15, ks * 64 + l4 * 16));

    // O += P V from global V^T fragments
    #pragma unroll
    for (int dj = 0; dj < 4; ++dj)
      #pragma unroll
      for (int ks = 0; ks < 2; ++ks) {
        bf16x8 vf = *(const bf16x8*)(Vg + (long)(dj * 16 + l15) * 1024 + k0 + ks * 32 + l4 * 8);
        oacc[dj] = __builtin_amdgcn_mfma_f32_16x16x32_bf16(pf[ks], vf, oacc[dj], 0, 0, 0);
      }
  }

  // normalize + store (B,G,512) bf16
  #pragma unroll
  for (int dj = 0; dj < 4; ++dj)
    #pragma unroll
    for (int i = 0; i < 4; ++i) {
      int gq = qw + (l4 << 2) + i;
      int dd = dj * 16 + l15;
      float o = oacc[dj][i] / lrun[i];
      AO[((long)((b << 10) + gq)) * 512 + h * 64 + dd] = f2bf(o);
    }
}

// ---------------- output projection: out = AO @ Wo^T + bo (fp32 out) ------------
__global__ __launch_bounds__(256)
void k_gemm_out(const unsigned short* __restrict__ AO, const unsigned short* __restrict__ WO,
                const float* __restrict__ bo, float* __restrict__ out)
{
  __shared__ unsigned short ldsA[128 * 32];
  __shared__ unsigned short ldsB[64 * 32];
  int m0 = blockIdx.x * 128, n0 = blockIdx.y * 64;
  f32x4 acc[4][2];
  gemm_core64(AO, WO, m0, n0, ldsA, ldsB, acc);

  const int t = threadIdx.x, lane = t & 63, w = t >> 6;
  const int wm = (w >> 1) << 6, wn = (w & 1) << 5;
  const int l15 = lane & 15, l4 = lane >> 4;
  #pragma unroll
  for (int r = 0; r < 4; ++r)
    #pragma unroll
    for (int c = 0; c < 2; ++c)
      #pragma unroll
      for (int i = 0; i < 4; ++i) {
        int m = m0 + wm + r * 16 + (l4 << 2) + i;
        int n = n0 + wn + c * 16 + l15;
        out[(long)m * 512 + n] = acc[r][c][i] + bo[n];
      }
}

// ---------------- launch ---------------------------------------------------------
extern "C" void kernel_launch(void* const* d_in, const int* in_sizes, int n_in,
                              void* d_out, int out_size, void* d_ws, size_t ws_size,
                              hipStream_t stream) {
  const float* q      = (const float*)d_in[0];
  const float* k      = (const float*)d_in[1];
  const float* v      = (const float*)d_in[2];
  const float* coords = (const float*)d_in[3];
  const int*   mask   = (const int*)d_in[4];
  const float* Wq     = (const float*)d_in[5];
  const float* bq     = (const float*)d_in[6];
  const float* Wk     = (const float*)d_in[7];
  const float* bk     = (const float*)d_in[8];
  const float* Wv     = (const float*)d_in[9];
  const float* bv     = (const float*)d_in[10];
  const float* Wo     = (const float*)d_in[11];
  const float* bo     = (const float*)d_in[12];
  const float* rpe_x  = (const float*)d_in[13];
  const float* rpe_y  = (const float*)d_in[14];
  float* out = (float*)d_out;

  unsigned short* WQB  = (unsigned short*)d_ws;
  unsigned short* WKB  = WQB + 262144;
  unsigned short* WVB  = WKB + 262144;
  unsigned short* WOB  = WVB + 262144;
  unsigned short* XQ   = WOB + 262144;   // 3x2097152; dead after proj
  unsigned short* XK   = XQ + 2097152;
  unsigned short* XV   = XK + 2097152;
  unsigned short* QP   = XV + 2097152;
  unsigned short* KP   = QP + 2097152;
  unsigned short* VTMP = KP + 2097152;
  unsigned short* KC   = VTMP + 2097152;
  unsigned short* VCT  = KC + 2097152;
  unsigned short* AO   = VCT + 2097152;
  int* idxp            = (int*)(AO + 2097152);   // 4096 ints
  int* cntp            = idxp + 4096;            // 4 ints
  unsigned short* BUKC = XQ;   // alias: written after proj consumed XQ..XV (8.4MB < 12.6MB)

  k_cvt_all<<<dim3(3584), dim3(256), 0, stream>>>(q, k, v, Wq, Wk, Wv, Wo,
                                                  XQ, XK, XV, WQB, WKB, WVB, WOB);
  k_scan<<<dim3(4), dim3(1024), 0, stream>>>(mask, idxp, cntp);
  k_gemm_proj<<<dim3(32, 8, 3), dim3(256), 0, stream>>>(XQ, XK, XV, WQB, WKB, WVB,
                                                        bq, bk, bv, QP, KP, VTMP);
  k_gatherKV<<<dim3(16, 32), dim3(256), 0, stream>>>(KP, VTMP, idxp, cntp, KC, VCT);
  k_buckets_c<<<dim3(4096, 4), dim3(256), 0, stream>>>(coords, idxp, cntp, BUKC);
  k_attn<<<dim3(512), dim3(256), 0, stream>>>(QP, KC, VCT, BUKC, cntp,
                                              rpe_x, rpe_y, AO);
  k_gemm_out<<<dim3(32, 8), dim3(256), 0, stream>>>(AO, WOB, bo, out);
}